// Round 21
// baseline (91.385 us; speedup 1.0000x reference)
//
#include <hip/hip_runtime.h>
#include <hip/hip_bf16.h>
#include <cstddef>

#define BB 4
#define CC 64
#define UU 5
#define VV 5
#define HH 64
#define WW 64

typedef float f4v __attribute__((ext_vector_type(4)));

__device__ __forceinline__ float rdlane(float v, int l) {
    return __uint_as_float((unsigned)__builtin_amdgcn_readlane((int)__float_as_uint(v), l));
}
__device__ __forceinline__ float rfl(float v) {
    return __uint_as_float((unsigned)__builtin_amdgcn_readfirstlane((int)__float_as_uint(v)));
}
__device__ __forceinline__ float sum4(float4 a) { return (a.x+a.y)+(a.z+a.w); }
__device__ __forceinline__ void nt_store4(float4 r, float4* p) {
    union { float4 s; f4v v; } u; u.s = r;
    __builtin_nontemporal_store(u.v, (f4v*)p);
}

// ---------------------------------------------------------------------------
// K1 (R21): 1024 blocks = (bc, qt) x 256 threads. BURST-25: each thread
// issues all 25 tile loads back-to-back into statically-indexed q[25]
// (~100 VGPRs, deep load clause, ~1.2MB in flight/CU), THEN consumes.
// No launch_bounds min-waves (R10's (256,4) cap caused the 45MB spill).
// LDS 25.6KB -> 3 blocks/CU (VGPR-bound).
//   m_hw[bc*4096 + p]                  final /25 (direct)
//   R[(bc*25+k)*64 + qt*16 + hloc]     UNSCALED row sums (complete)
//   vw_part[(bc*4+qt)*320 + v*64 + w]  UNSCALED col sums over block's 16 h
// Scratch lives in d_out (k3 rewrites it).
// ---------------------------------------------------------------------------
__global__ __launch_bounds__(256) void k1_means(const float* __restrict__ x,
        float* __restrict__ m_hw, float* __restrict__ R,
        float* __restrict__ vw_part) {
    const int bid = blockIdx.x;       // bc*4 + qt
    const int bc  = bid >> 2;
    const int qt  = bid & 3;
    const int t    = threadIdx.x;     // 0..255
    const int p    = qt*256 + t;      // quad index in tile, 0..1023
    const int wave = t >> 6;
    const int lane = t & 63;

    const float4* xt = (const float4*)x + (size_t)bc * 25600 + p;

    __shared__ float smem[25*256];    // 25.6 KB: [tile][thread] quad-sums

    // ---- burst: 25 independent loads, statically indexed (stays in VGPRs)
    float4 q[25];
    #pragma unroll
    for (int k = 0; k < 25; ++k)
        q[k] = xt[(size_t)k*1024];

    // ---- consume
    float4 hw = make_float4(0.f,0.f,0.f,0.f);
    float4 vwacc[5];
    #pragma unroll
    for (int v = 0; v < 5; ++v) vwacc[v] = make_float4(0.f,0.f,0.f,0.f);
    #pragma unroll
    for (int k = 0; k < 25; ++k) {
        hw.x += q[k].x; hw.y += q[k].y; hw.z += q[k].z; hw.w += q[k].w;
        const int v = k % 5;          // compile-time (unrolled)
        vwacc[v].x += q[k].x; vwacc[v].y += q[k].y;
        vwacc[v].z += q[k].z; vwacc[v].w += q[k].w;
        smem[k*256 + t] = sum4(q[k]);
    }

    // m_hw final (full 25-tile sum at quad p), /25
    float4 o;
    o.x = hw.x*(1.f/25.f); o.y = hw.y*(1.f/25.f);
    o.z = hw.z*(1.f/25.f); o.w = hw.w*(1.f/25.f);
    ((float4*)m_hw)[(size_t)bc*1024 + p] = o;

    __syncthreads();

    // R row-sums: 400 tasks = 25 tiles x 16 local rows
    for (int task = t; task < 400; task += 256) {
        const int k    = task >> 4;
        const int hloc = task & 15;
        const float* row = &smem[k*256 + hloc*16];
        float s = 0.f;
        #pragma unroll
        for (int j = 0; j < 16; ++j) s += row[j];
        R[((size_t)bc*25 + k)*64 + qt*16 + hloc] = s;
    }
    __syncthreads();

    // vw: per-wave fold (4 h-rows) via shuffles, then cross-wave via LDS
    float4* vwbuf = (float4*)smem;    // [wave][v][16] float4 (5KB reuse)
    #pragma unroll
    for (int v = 0; v < 5; ++v) {
        float4 s = vwacc[v];
        s.x += __shfl_xor(s.x, 16); s.y += __shfl_xor(s.y, 16);
        s.z += __shfl_xor(s.z, 16); s.w += __shfl_xor(s.w, 16);
        s.x += __shfl_xor(s.x, 32); s.y += __shfl_xor(s.y, 32);
        s.z += __shfl_xor(s.z, 32); s.w += __shfl_xor(s.w, 32);
        if (lane < 16) vwbuf[(wave*5 + v)*16 + lane] = s;
    }
    __syncthreads();

    if (t < 80) {     // fold 4 waves -> per-(bc,qt) vw partial (16 h rows)
        const int v = t >> 4;
        float4 s = vwbuf[(0*5 + v)*16 + (t & 15)];
        #pragma unroll
        for (int w4 = 1; w4 < 4; ++w4) {
            float4 pp = vwbuf[(w4*5 + v)*16 + (t & 15)];
            s.x += pp.x; s.y += pp.y; s.z += pp.z; s.w += pp.w;
        }
        ((float4*)vw_part)[(size_t)bid*80 + t] = s;
    }
}

// ---------------------------------------------------------------------------
// K2 (R19-proven, 23-col chunks; A-bot folds 4 vw quarter-partials):
// 276 rows x 3 chunks = 828 blocks (< 1024 SIMDs -> no straggler tail).
// 64 threads; (64,1): weights stay in VGPRs.
// ---------------------------------------------------------------------------
#define LOADROW(dst, src)                                              \
    { _Pragma("unroll")                                                \
      for (int q = 0; q < 16; ++q) {                                   \
          float4 t4 = ((const float4*)(src))[lane*16 + q];             \
          dst[4*q+0] = t4.x; dst[4*q+1] = t4.y;                        \
          dst[4*q+2] = t4.z; dst[4*q+3] = t4.w;                        \
      } }

#define DOT64(res, wr, src)                                            \
    float res;                                                         \
    { float _a0=0.f,_a1=0.f,_a2=0.f,_a3=0.f;                           \
      _Pragma("unroll")                                                \
      for (int cc2 = 0; cc2 < 64; cc2 += 4) {                          \
          _a0 = fmaf(wr[cc2+0], rdlane(src, cc2+0), _a0);              \
          _a1 = fmaf(wr[cc2+1], rdlane(src, cc2+1), _a1);              \
          _a2 = fmaf(wr[cc2+2], rdlane(src, cc2+2), _a2);              \
          _a3 = fmaf(wr[cc2+3], rdlane(src, cc2+3), _a3);              \
      }                                                                \
      res = (_a0 + _a1) + (_a2 + _a3); }

#define MLP_CORE(VIN, OUTEXPR)                                         \
    {                                                                  \
        float v = (VIN);                                               \
        DOT64(d1, w1r, v);                                             \
        float acc1 = d1 + b1v;                                         \
        float ya = acc1 / (1.f + __expf(-acc1));                       \
        DOT64(d2, w2r, ya);                                            \
        float acc2 = d2 + b2v;                                         \
        DOT64(d3, fr, acc2);                                           \
        OUTEXPR = d3 + fbv;                                            \
    }

__global__ __launch_bounds__(64, 1) void k2_mlp(
        const float* __restrict__ m_hw, const float* __restrict__ R,
        const float* __restrict__ vw_part,
        const float* __restrict__ w1, const float* __restrict__ b1,
        const float* __restrict__ w2, const float* __restrict__ b2,
        const float* __restrict__ fw0, const float* __restrict__ fb0,
        const float* __restrict__ fw1, const float* __restrict__ fb1,
        const float* __restrict__ fw2, const float* __restrict__ fb2,
        const float* __restrict__ fw3, const float* __restrict__ fb3,
        float* __restrict__ mod_hw, float* __restrict__ mod_uh,
        float* __restrict__ mod_vw, float* __restrict__ mod_uv) {
    const int blk  = blockIdx.x;          // row*3 + chunk
    const int row  = blk / 3;             // 0..275
    const int chnk = blk % 3;
    const int b    = row / 69;
    const int i    = row % 69;
    const int lane = threadIdx.x & 63;

    const int j0 = chnk * 23;
    const int j1 = min(69, j0 + 23);
    const bool top = (i < 64);

    const float* fwA = top ? fw0 : fw3;
    const float* fbA = top ? fb0 : fb3;
    const float* fwB = top ? fw2 : fw1;
    const float* fbB = top ? fb2 : fb1;

    float w1r[64], w2r[64], fr[64];
    LOADROW(w1r, w1);
    LOADROW(w2r, w2);
    const float b1v = b1[lane];
    const float b2v = b2[lane];

    const int b64c = b * CC + lane;       // (b,c) slab index for gathers
    const int cbl  = b64c;

    const int jm = min(j1, 64);
    if (j0 < jm) {                        // region A: j < 64
        LOADROW(fr, fwA);
        const float fbv = fbA[lane];
        if (top) {
            const float* src = m_hw + (size_t)b64c*4096 + i*64;
            float* sp = mod_hw + ((size_t)cbl*64 + i)*64;
            for (int j = j0; j < jm; ++j)
                MLP_CORE(src[j], sp[j])
        } else {
            const float* pv = vw_part + (size_t)b64c*4*320 + (i-64)*64;
            float* sp = mod_vw + (size_t)cbl*320 + (i-64)*64;
            for (int j = j0; j < jm; ++j) {
                float vin = ((pv[j] + pv[320 + j]) + (pv[640 + j] + pv[960 + j]))
                            * (1.f/320.f);
                MLP_CORE(vin, sp[j])
            }
        }
    }
    if (j1 > 64) {                        // region B: j >= 64
        LOADROW(fr, fwB);
        const float fbv = fbB[lane];
        const int jb = max(j0, 64);
        if (top) {
            float* sp = mod_uh + (size_t)cbl*320 + i;
            for (int j = jb; j < j1; ++j) {
                const int u = j - 64;
                const float* Rp = R + ((size_t)b64c*25 + u*5)*64 + i;
                float vin = (Rp[0] + Rp[64] + Rp[128] + Rp[192] + Rp[256])
                            * (1.f/320.f);
                MLP_CORE(vin, sp[(size_t)u*64])
            }
        } else {
            float* sp = mod_uv + (size_t)cbl*25 + (i-64);
            for (int j = jb; j < j1; ++j) {
                const int u = j - 64;
                const float4* Rp4 = (const float4*)(R
                    + ((size_t)b64c*25 + u*5 + (i-64))*64);
                float4 a = make_float4(0.f,0.f,0.f,0.f);
                #pragma unroll
                for (int k = 0; k < 16; ++k) {
                    float4 pp = Rp4[k];
                    a.x += pp.x; a.y += pp.y; a.z += pp.z; a.w += pp.w;
                }
                MLP_CORE(sum4(a) * (1.f/4096.f), sp[(size_t)u*5])
            }
        }
    }
}

// ---------------------------------------------------------------------------
// K3 (unchanged, passing): out = x * (mod_hw + mod_uv + mod_uh + mod_vw)
// 1024 blocks = (bc, quarter), 256 threads, 4 blocks/CU.
// ---------------------------------------------------------------------------
__global__ __launch_bounds__(256, 4) void k3_apply(
        const float* __restrict__ x,
        const float* __restrict__ mod_hw, const float* __restrict__ mod_uh,
        const float* __restrict__ mod_vw, const float* __restrict__ mod_uv,
        float* __restrict__ out) {
    const int blk  = blockIdx.x;          // bc*4 + quarter
    const int bc   = blk >> 2;
    const int qt   = blk & 3;
    const int t    = threadIdx.x;         // 0..255
    const int base = qt*256 + t;          // quad index in tile, 0..1023
    const int h    = base >> 4;           // 0..63

    float4 mh = ((const float4*)(mod_hw + (size_t)bc * 4096))[base];
    float uh[5];
    #pragma unroll
    for (int u = 0; u < 5; ++u) uh[u] = mod_uh[(size_t)bc*320 + u*64 + h];
    float4 vw[5];
    #pragma unroll
    for (int v = 0; v < 5; ++v)
        vw[v] = ((const float4*)(mod_vw + (size_t)bc*320 + v*64))[t & 15];
    float uv[25];
    #pragma unroll
    for (int k = 0; k < 25; ++k)
        uv[k] = rfl(mod_uv[(size_t)bc*25 + k]);   // uniform -> SGPR

    const float4* x4 = (const float4*)(x + (size_t)bc * (UU*VV*HH*WW));
    float4* o4 = (float4*)(out + (size_t)bc * (UU*VV*HH*WW));

    #pragma unroll
    for (int u = 0; u < 5; ++u) {
        #pragma unroll
        for (int v = 0; v < 5; ++v) {
            const int idx = (u*5 + v)*1024 + base;
            float4 xv = x4[idx];
            const float s = uh[u] + uv[u*5 + v];
            float4 r;
            r.x = xv.x * (mh.x + vw[v].x + s);
            r.y = xv.y * (mh.y + vw[v].y + s);
            r.z = xv.z * (mh.z + vw[v].z + s);
            r.w = xv.w * (mh.w + vw[v].w + s);
            nt_store4(r, &o4[idx]);
        }
    }
}

// ---------------------------------------------------------------------------
extern "C" void kernel_launch(void* const* d_in, const int* in_sizes, int n_in,
                              void* d_out, int out_size, void* d_ws, size_t ws_size,
                              hipStream_t stream) {
    const float* x   = (const float*)d_in[0];
    const float* w1  = (const float*)d_in[1];
    const float* b1  = (const float*)d_in[2];
    const float* w2  = (const float*)d_in[3];
    const float* b2  = (const float*)d_in[4];
    const float* fw0 = (const float*)d_in[5];
    const float* fb0 = (const float*)d_in[6];
    const float* fw1 = (const float*)d_in[7];
    const float* fb1 = (const float*)d_in[8];
    const float* fw2 = (const float*)d_in[9];
    const float* fb2 = (const float*)d_in[10];
    const float* fw3 = (const float*)d_in[11];
    const float* fb3 = (const float*)d_in[12];

    float* ws = (float*)d_ws;
    float* mod_hw = ws;                        // 256*4096       = 1,048,576
    float* mod_uh = mod_hw + 1048576;          // 256*320        =    81,920
    float* mod_vw = mod_uh + 81920;            // 256*320        =    81,920
    float* mod_uv = mod_vw + 81920;            // 256*25         =     6,400

    // d_out doubles as scratch for k1 outputs (k3 fully rewrites it).
    float* m_hw    = (float*)d_out;            // 256*4096       = 1,048,576
    float* Rbuf    = m_hw + 1048576;           // 256*25*64      =   409,600
    float* vw_part = Rbuf + 409600;            // 1024*320       =   327,680

    k1_means<<<BB*CC*4, 256, 0, stream>>>(x, m_hw, Rbuf, vw_part);
    k2_mlp<<<BB*69*3, 64, 0, stream>>>(m_hw, Rbuf, vw_part, w1, b1, w2, b2,
                                       fw0, fb0, fw1, fb1, fw2, fb2, fw3, fb3,
                                       mod_hw, mod_uh, mod_vw, mod_uv);
    k3_apply<<<BB*CC*4, 256, 0, stream>>>(x, mod_hw, mod_uh, mod_vw, mod_uv,
                                          (float*)d_out);
}

// Round 22
// 87.504 us; speedup vs baseline: 1.0444x; 1.0444x over previous
//
#include <hip/hip_runtime.h>
#include <hip/hip_bf16.h>
#include <cstddef>

#define BB 4
#define CC 64
#define UU 5
#define VV 5
#define HH 64
#define WW 64

typedef float f4v __attribute__((ext_vector_type(4)));

__device__ __forceinline__ float rdlane(float v, int l) {
    return __uint_as_float((unsigned)__builtin_amdgcn_readlane((int)__float_as_uint(v), l));
}
__device__ __forceinline__ float rfl(float v) {
    return __uint_as_float((unsigned)__builtin_amdgcn_readfirstlane((int)__float_as_uint(v)));
}
__device__ __forceinline__ float sum4(float4 a) { return (a.x+a.y)+(a.z+a.w); }
__device__ __forceinline__ void nt_store4(float4 r, float4* p) {
    union { float4 s; f4v v; } u; u.s = r;
    __builtin_nontemporal_store(u.v, (f4v*)p);
}

// ---------------------------------------------------------------------------
// K1 (R22 = R19 + LDS pad): 512 blocks = (bc, half), 256 threads.
// R-phase row stride padded 16 -> 17 floats: read banks (hloc*17+j)%32 with
// 17 coprime 32 -> conflict-free (was 16-way, ~5.7x, between two barriers).
// LDS 54.4KB -> 2 blocks/CU; grid is exactly 2/CU so no occupancy loss.
//   m_hw[bc*4096 + p]             final /25 (direct)
//   R[(bc*25+k)*64 + h]           UNSCALED row sums; h = half*32 + hloc
//   vw_part[(bc*2+half)*320 + v*64 + w]  UNSCALED col sums over 32 h
// ---------------------------------------------------------------------------
__global__ __launch_bounds__(256) void k1_means(const float* __restrict__ x,
        float* __restrict__ m_hw, float* __restrict__ R,
        float* __restrict__ vw_part) {
    const int bid  = blockIdx.x;      // bc*2 + half
    const int bc   = bid >> 1;
    const int half = bid & 1;
    const int t    = threadIdx.x;     // 0..255
    const int wave = t >> 6;
    const int lane = t & 63;

    const float4* xs = (const float4*)x + (size_t)bc * 25600
                     + (size_t)half * 512;

    __shared__ float smem[25*544];    // 54.4 KB: [tile][32 rows x 17 (pad)]

    float4 hwacc[2];
    hwacc[0] = make_float4(0.f,0.f,0.f,0.f);
    hwacc[1] = make_float4(0.f,0.f,0.f,0.f);
    float4 vwacc[5];
    #pragma unroll
    for (int v = 0; v < 5; ++v) vwacc[v] = make_float4(0.f,0.f,0.f,0.f);

    #pragma unroll
    for (int u = 0; u < 5; ++u) {
        #pragma unroll
        for (int v = 0; v < 5; ++v) {
            const int k = u*5 + v;
            #pragma unroll
            for (int r = 0; r < 2; ++r) {
                float4 q = xs[(size_t)k*1024 + r*256 + t];
                hwacc[r].x += q.x; hwacc[r].y += q.y;
                hwacc[r].z += q.z; hwacc[r].w += q.w;
                vwacc[v].x += q.x; vwacc[v].y += q.y;
                vwacc[v].z += q.z; vwacc[v].w += q.w;
                // padded: row hloc = r*16 + (t>>4), col j = t&15
                smem[k*544 + (r*16 + (t>>4))*17 + (t & 15)] = sum4(q);
            }
        }
    }

    #pragma unroll
    for (int r = 0; r < 2; ++r) {
        float4 o;
        o.x = hwacc[r].x*(1.f/25.f); o.y = hwacc[r].y*(1.f/25.f);
        o.z = hwacc[r].z*(1.f/25.f); o.w = hwacc[r].w*(1.f/25.f);
        ((float4*)m_hw)[(size_t)bc*1024 + half*512 + r*256 + t] = o;
    }

    __syncthreads();

    // R row-sums: 800 tasks = 25 tiles x 32 local rows (conflict-free reads)
    for (int task = t; task < 800; task += 256) {
        const int k    = task >> 5;
        const int hloc = task & 31;
        const float* row = &smem[k*544 + hloc*17];
        float s = 0.f;
        #pragma unroll
        for (int j = 0; j < 16; ++j) s += row[j];
        R[((size_t)bc*25 + k)*64 + half*32 + hloc] = s;
    }
    __syncthreads();

    float4* vwbuf = (float4*)smem;
    #pragma unroll
    for (int v = 0; v < 5; ++v) {
        float4 s = vwacc[v];
        s.x += __shfl_xor(s.x, 16); s.y += __shfl_xor(s.y, 16);
        s.z += __shfl_xor(s.z, 16); s.w += __shfl_xor(s.w, 16);
        s.x += __shfl_xor(s.x, 32); s.y += __shfl_xor(s.y, 32);
        s.z += __shfl_xor(s.z, 32); s.w += __shfl_xor(s.w, 32);
        if (lane < 16) vwbuf[(wave*5 + v)*16 + lane] = s;
    }
    __syncthreads();

    if (t < 80) {
        const int v = t >> 4;
        float4 s = vwbuf[(0*5 + v)*16 + (t & 15)];
        #pragma unroll
        for (int w4 = 1; w4 < 4; ++w4) {
            float4 pp = vwbuf[(w4*5 + v)*16 + (t & 15)];
            s.x += pp.x; s.y += pp.y; s.z += pp.z; s.w += pp.w;
        }
        ((float4*)vw_part)[(size_t)bid*80 + t] = s;
    }
}

// ---------------------------------------------------------------------------
// K2 (R19 verbatim, passing): 276 rows x 3 chunks = 828 blocks, 64 threads.
// ---------------------------------------------------------------------------
#define LOADROW(dst, src)                                              \
    { _Pragma("unroll")                                                \
      for (int q = 0; q < 16; ++q) {                                   \
          float4 t4 = ((const float4*)(src))[lane*16 + q];             \
          dst[4*q+0] = t4.x; dst[4*q+1] = t4.y;                        \
          dst[4*q+2] = t4.z; dst[4*q+3] = t4.w;                        \
      } }

#define DOT64(res, wr, src)                                            \
    float res;                                                         \
    { float _a0=0.f,_a1=0.f,_a2=0.f,_a3=0.f;                           \
      _Pragma("unroll")                                                \
      for (int cc2 = 0; cc2 < 64; cc2 += 4) {                          \
          _a0 = fmaf(wr[cc2+0], rdlane(src, cc2+0), _a0);              \
          _a1 = fmaf(wr[cc2+1], rdlane(src, cc2+1), _a1);              \
          _a2 = fmaf(wr[cc2+2], rdlane(src, cc2+2), _a2);              \
          _a3 = fmaf(wr[cc2+3], rdlane(src, cc2+3), _a3);              \
      }                                                                \
      res = (_a0 + _a1) + (_a2 + _a3); }

#define MLP_CORE(VIN, OUTEXPR)                                         \
    {                                                                  \
        float v = (VIN);                                               \
        DOT64(d1, w1r, v);                                             \
        float acc1 = d1 + b1v;                                         \
        float ya = acc1 / (1.f + __expf(-acc1));                       \
        DOT64(d2, w2r, ya);                                            \
        float acc2 = d2 + b2v;                                         \
        DOT64(d3, fr, acc2);                                           \
        OUTEXPR = d3 + fbv;                                            \
    }

__global__ __launch_bounds__(64, 1) void k2_mlp(
        const float* __restrict__ m_hw, const float* __restrict__ R,
        const float* __restrict__ vw_part,
        const float* __restrict__ w1, const float* __restrict__ b1,
        const float* __restrict__ w2, const float* __restrict__ b2,
        const float* __restrict__ fw0, const float* __restrict__ fb0,
        const float* __restrict__ fw1, const float* __restrict__ fb1,
        const float* __restrict__ fw2, const float* __restrict__ fb2,
        const float* __restrict__ fw3, const float* __restrict__ fb3,
        float* __restrict__ mod_hw, float* __restrict__ mod_uh,
        float* __restrict__ mod_vw, float* __restrict__ mod_uv) {
    const int blk  = blockIdx.x;          // row*3 + chunk
    const int row  = blk / 3;             // 0..275
    const int chnk = blk % 3;
    const int b    = row / 69;
    const int i    = row % 69;
    const int lane = threadIdx.x & 63;

    const int j0 = chnk * 23;
    const int j1 = min(69, j0 + 23);
    const bool top = (i < 64);

    const float* fwA = top ? fw0 : fw3;
    const float* fbA = top ? fb0 : fb3;
    const float* fwB = top ? fw2 : fw1;
    const float* fbB = top ? fb2 : fb1;

    float w1r[64], w2r[64], fr[64];
    LOADROW(w1r, w1);
    LOADROW(w2r, w2);
    const float b1v = b1[lane];
    const float b2v = b2[lane];

    const int b64c = b * CC + lane;       // (b,c) slab index for gathers
    const int cbl  = b64c;

    const int jm = min(j1, 64);
    if (j0 < jm) {                        // region A: j < 64
        LOADROW(fr, fwA);
        const float fbv = fbA[lane];
        if (top) {
            const float* src = m_hw + (size_t)b64c*4096 + i*64;
            float* sp = mod_hw + ((size_t)cbl*64 + i)*64;
            for (int j = j0; j < jm; ++j)
                MLP_CORE(src[j], sp[j])
        } else {
            const float* q0 = vw_part + ((size_t)b64c*2 + 0)*320 + (i-64)*64;
            const float* q1 = vw_part + ((size_t)b64c*2 + 1)*320 + (i-64)*64;
            float* sp = mod_vw + (size_t)cbl*320 + (i-64)*64;
            for (int j = j0; j < jm; ++j)
                MLP_CORE((q0[j] + q1[j]) * (1.f/320.f), sp[j])
        }
    }
    if (j1 > 64) {                        // region B: j >= 64
        LOADROW(fr, fwB);
        const float fbv = fbB[lane];
        const int jb = max(j0, 64);
        if (top) {
            float* sp = mod_uh + (size_t)cbl*320 + i;
            for (int j = jb; j < j1; ++j) {
                const int u = j - 64;
                const float* Rp = R + ((size_t)b64c*25 + u*5)*64 + i;
                float vin = (Rp[0] + Rp[64] + Rp[128] + Rp[192] + Rp[256])
                            * (1.f/320.f);
                MLP_CORE(vin, sp[(size_t)u*64])
            }
        } else {
            float* sp = mod_uv + (size_t)cbl*25 + (i-64);
            for (int j = jb; j < j1; ++j) {
                const int u = j - 64;
                const float4* Rp4 = (const float4*)(R
                    + ((size_t)b64c*25 + u*5 + (i-64))*64);
                float4 a = make_float4(0.f,0.f,0.f,0.f);
                #pragma unroll
                for (int k = 0; k < 16; ++k) {
                    float4 pp = Rp4[k];
                    a.x += pp.x; a.y += pp.y; a.z += pp.z; a.w += pp.w;
                }
                MLP_CORE(sum4(a) * (1.f/4096.f), sp[(size_t)u*5])
            }
        }
    }
}

// ---------------------------------------------------------------------------
// K3 (R22 = R19 + XCD grouping): 1024 blocks, 256 threads, 4 blocks/CU.
// Bijective remap lb = (pb&7)*128 + (pb>>3): the 4 quarter-blocks sharing one
// bc's mod set (~19KB) land on the SAME XCD L2 (1024%8==0, T1-style).
// ---------------------------------------------------------------------------
__global__ __launch_bounds__(256, 4) void k3_apply(
        const float* __restrict__ x,
        const float* __restrict__ mod_hw, const float* __restrict__ mod_uh,
        const float* __restrict__ mod_vw, const float* __restrict__ mod_uv,
        float* __restrict__ out) {
    const int pb   = blockIdx.x;          // physical block id
    const int lb   = (pb & 7)*128 + (pb >> 3);   // logical: bc*4 + quarter
    const int bc   = lb >> 2;
    const int qt   = lb & 3;
    const int t    = threadIdx.x;         // 0..255
    const int base = qt*256 + t;          // quad index in tile, 0..1023
    const int h    = base >> 4;           // 0..63

    float4 mh = ((const float4*)(mod_hw + (size_t)bc * 4096))[base];
    float uh[5];
    #pragma unroll
    for (int u = 0; u < 5; ++u) uh[u] = mod_uh[(size_t)bc*320 + u*64 + h];
    float4 vw[5];
    #pragma unroll
    for (int v = 0; v < 5; ++v)
        vw[v] = ((const float4*)(mod_vw + (size_t)bc*320 + v*64))[t & 15];
    float uv[25];
    #pragma unroll
    for (int k = 0; k < 25; ++k)
        uv[k] = rfl(mod_uv[(size_t)bc*25 + k]);   // uniform -> SGPR

    const float4* x4 = (const float4*)(x + (size_t)bc * (UU*VV*HH*WW));
    float4* o4 = (float4*)(out + (size_t)bc * (UU*VV*HH*WW));

    #pragma unroll
    for (int u = 0; u < 5; ++u) {
        #pragma unroll
        for (int v = 0; v < 5; ++v) {
            const int idx = (u*5 + v)*1024 + base;
            float4 xv = x4[idx];
            const float s = uh[u] + uv[u*5 + v];
            float4 r;
            r.x = xv.x * (mh.x + vw[v].x + s);
            r.y = xv.y * (mh.y + vw[v].y + s);
            r.z = xv.z * (mh.z + vw[v].z + s);
            r.w = xv.w * (mh.w + vw[v].w + s);
            nt_store4(r, &o4[idx]);
        }
    }
}

// ---------------------------------------------------------------------------
extern "C" void kernel_launch(void* const* d_in, const int* in_sizes, int n_in,
                              void* d_out, int out_size, void* d_ws, size_t ws_size,
                              hipStream_t stream) {
    const float* x   = (const float*)d_in[0];
    const float* w1  = (const float*)d_in[1];
    const float* b1  = (const float*)d_in[2];
    const float* w2  = (const float*)d_in[3];
    const float* b2  = (const float*)d_in[4];
    const float* fw0 = (const float*)d_in[5];
    const float* fb0 = (const float*)d_in[6];
    const float* fw1 = (const float*)d_in[7];
    const float* fb1 = (const float*)d_in[8];
    const float* fw2 = (const float*)d_in[9];
    const float* fb2 = (const float*)d_in[10];
    const float* fw3 = (const float*)d_in[11];
    const float* fb3 = (const float*)d_in[12];

    float* ws = (float*)d_ws;
    float* mod_hw = ws;                        // 256*4096       = 1,048,576
    float* mod_uh = mod_hw + 1048576;          // 256*320        =    81,920
    float* mod_vw = mod_uh + 81920;            // 256*320        =    81,920
    float* mod_uv = mod_vw + 81920;            // 256*25         =     6,400

    // d_out doubles as scratch for k1 outputs (k3 fully rewrites it).
    float* m_hw    = (float*)d_out;            // 256*4096       = 1,048,576
    float* Rbuf    = m_hw + 1048576;           // 256*25*64      =   409,600
    float* vw_part = Rbuf + 409600;            // 512*320        =   163,840

    k1_means<<<BB*CC*2, 256, 0, stream>>>(x, m_hw, Rbuf, vw_part);
    k2_mlp<<<BB*69*3, 64, 0, stream>>>(m_hw, Rbuf, vw_part, w1, b1, w2, b2,
                                       fw0, fb0, fw1, fb1, fw2, fb2, fw3, fb3,
                                       mod_hw, mod_uh, mod_vw, mod_uv);
    k3_apply<<<BB*CC*4, 256, 0, stream>>>(x, mod_hw, mod_uh, mod_vw, mod_uv,
                                          (float*)d_out);
}